// Round 1
// baseline (2137.178 us; speedup 1.0000x reference)
//
#include <hip/hip_runtime.h>

#define B_ 1024
#define M_ 64
#define N_ 8192
#define NSG 16   // n-splits for k_G   (range 512 each)
#define NS3 8    // n-splits for k_H3  (range 1024 each)

// ---------------------------------------------------------------------------
// zero the imaginary rows of out-x: out[(2b+1)*N + n] = 0
__global__ __launch_bounds__(256) void k_zero_imag(float* out) {
    int b = blockIdx.y;
    int n = (blockIdx.x * 256 + threadIdx.x) * 4;
    float4 z = make_float4(0.f, 0.f, 0.f, 0.f);
    *(float4*)(out + (size_t)(2 * b + 1) * N_ + n) = z;
}

// ---------------------------------------------------------------------------
// S[i][j] (complex, row-major 64x64, float2) = I/(rho+1e-12) + A A^H
// AAHT[k][m] = (A A^H)[m][k]   (transposed storage, float2)
__global__ __launch_bounds__(256) void k_Sbuild(const float* A, const float* lr,
                                                float* S, float* AAHT) {
    __shared__ float arI[N_];
    __shared__ float aiI[N_];
    __shared__ float red[8];
    int i = blockIdx.x, t = threadIdx.x;
    const float* Ar = A;
    const float* Ai = A + (size_t)M_ * N_;
    for (int j = t; j < N_; j += 256) {
        arI[j] = Ar[(size_t)i * N_ + j];
        aiI[j] = Ai[(size_t)i * N_ + j];
    }
    __syncthreads();
    float inv_rho = 1.0f / (expf(lr[0]) + 1e-12f);
    for (int jj = 0; jj < 64; ++jj) {
        float aR = 0.f, aI = 0.f;
        for (int nn = t; nn < N_; nn += 256) {
            float br = Ar[(size_t)jj * N_ + nn];
            float bi = Ai[(size_t)jj * N_ + nn];
            float xr = arI[nn], xi = aiI[nn];
            aR += xr * br + xi * bi;   // Re(AA^H)[i][jj]
            aI += xi * br - xr * bi;   // Im(AA^H)[i][jj]
        }
        for (int off = 32; off > 0; off >>= 1) {
            aR += __shfl_down(aR, off, 64);
            aI += __shfl_down(aI, off, 64);
        }
        int lane = t & 63, w = t >> 6;
        if (lane == 0) { red[w * 2] = aR; red[w * 2 + 1] = aI; }
        __syncthreads();
        if (t == 0) {
            float R = red[0] + red[2] + red[4] + red[6];
            float I = red[1] + red[3] + red[5] + red[7];
            S[(i * 64 + jj) * 2 + 0] = R + (i == jj ? inv_rho : 0.f);
            S[(i * 64 + jj) * 2 + 1] = I;
            AAHT[(jj * 64 + i) * 2 + 0] = R;   // AAHT[k=jj][m=i] = AAH[i][jj]... = AAH[m][k]? see note
            AAHT[(jj * 64 + i) * 2 + 1] = I;
        }
        __syncthreads();
    }
}
// note: block i computes row i of AAH; AAHT[jj*64+i] = AAH[i][jj], so a read of
// AAHT[k*64+m] returns AAH[m][k] as required by k_small12.

// ---------------------------------------------------------------------------
// complex Gauss-Jordan inverse of S (Hermitian PD, 64x64). Wt[k][m] = (S^-1)[m][k]
__global__ __launch_bounds__(256) void k_invert(const float* S, float* Wt) {
    __shared__ float2 Mg[64][128];
    __shared__ float2 fv[64];
    __shared__ float2 pinv_s;
    int t = threadIdx.x;
    for (int idx = t; idx < 4096; idx += 256) {
        int i = idx >> 6, j = idx & 63;
        Mg[i][j] = ((const float2*)S)[idx];
        Mg[i][64 + j] = (i == j) ? make_float2(1.f, 0.f) : make_float2(0.f, 0.f);
    }
    __syncthreads();
    for (int k = 0; k < 64; ++k) {
        if (t == 0) {
            float2 p = Mg[k][k];
            float d = p.x * p.x + p.y * p.y;
            pinv_s = make_float2(p.x / d, -p.y / d);
        }
        __syncthreads();
        if (t < 128) {
            float2 pv = pinv_s;
            float2 a = Mg[k][t];
            Mg[k][t] = make_float2(a.x * pv.x - a.y * pv.y, a.x * pv.y + a.y * pv.x);
        } else if (t < 192) {
            int i = t - 128;
            fv[i] = (i == k) ? make_float2(0.f, 0.f) : Mg[i][k];
        }
        __syncthreads();
        for (int idx = t; idx < 8192; idx += 256) {
            int i = idx >> 7, c = idx & 127;
            if (i != k) {
                float2 f = fv[i], r = Mg[k][c], a = Mg[i][c];
                Mg[i][c] = make_float2(a.x - (f.x * r.x - f.y * r.y),
                                       a.y - (f.x * r.y + f.y * r.x));
            }
        }
        __syncthreads();
    }
    for (int idx = t; idx < 4096; idx += 256) {
        int k = idx >> 6, m = idx & 63;
        ((float2*)Wt)[idx] = Mg[m][64 + k];
    }
}

// ---------------------------------------------------------------------------
// A_T[n][m][c] = A[c][m][n]  (so lanes-over-m read coalesced float2)
__global__ __launch_bounds__(256) void k_transpA(const float* A, float* AT) {
    __shared__ float tile[128][65];
    int n0 = blockIdx.x * 64;
    int t = threadIdx.x;
    int nl = t % 64, r0 = t / 64;
    for (int it = 0; it < 32; ++it) {
        int row = r0 + it * 4;                       // row = c*64+m
        tile[row][nl] = A[(size_t)row * N_ + n0 + nl];
    }
    __syncthreads();
    int j = t % 128, nn0 = t / 128;
    for (int it = 0; it < 32; ++it) {
        int nn = nn0 + it * 2;
        int m = j >> 1, c = j & 1;
        AT[((size_t)(n0 + nn) * 64 + m) * 2 + c] = tile[c * 64 + m][nn];
    }
}

// ---------------------------------------------------------------------------
// Gpart[split][b][c][m] : partial of G = A * r_n (complex), reduced over n-split
__global__ __launch_bounds__(256) void k_G(const float* AT, const float* rn, float* Gpart) {
    __shared__ float redL[4][2048];
    int t = threadIdx.x;
    int m = t & 63;
    int w = __builtin_amdgcn_readfirstlane(t >> 6);
    int split = blockIdx.x;
    int b0 = blockIdx.y * 16;
    int n0 = split * 512 + w * 128;
    float accR[16], accI[16];
#pragma unroll
    for (int b = 0; b < 16; ++b) { accR[b] = 0.f; accI[b] = 0.f; }
    for (int j = 0; j < 128; ++j) {
        int n = n0 + j;
        float2 a = *(const float2*)(AT + ((size_t)n * 64 + m) * 2);
#pragma unroll
        for (int b = 0; b < 16; ++b) {
            float rr = rn[((size_t)(b0 + b) * 2 + 0) * N_ + n];
            float ri = rn[((size_t)(b0 + b) * 2 + 1) * N_ + n];
            accR[b] += rr * a.x - ri * a.y;
            accI[b] += ri * a.x + rr * a.y;
        }
    }
#pragma unroll
    for (int b = 0; b < 16; ++b) {
        redL[w][b * 128 + m] = accR[b];
        redL[w][b * 128 + 64 + m] = accI[b];
    }
    __syncthreads();
    for (int k = t; k < 2048; k += 256) {
        float s = redL[0][k] + redL[1][k] + redL[2][k] + redL[3][k];
        int bl = k >> 7, rem = k & 127;
        Gpart[(size_t)split * 131072 + (size_t)(b0 + bl) * 128 + rem] = s;
    }
}

// ---------------------------------------------------------------------------
// per-step small: Ab = sum(Gpart) + rho*AAH*(z-u);  q = rho*(z-u) - S^-1*Ab
__global__ __launch_bounds__(256) void k_small12(const float* Gpart, const float* AAHT,
                                                 const float* Wt, const float* zin,
                                                 const float* uin, const float* lr, float* q) {
    __shared__ float2 AbS[4][64];
    int t = threadIdx.x;
    int m = t & 63;
    int w = __builtin_amdgcn_readfirstlane(t >> 6);
    int b = blockIdx.x * 4 + w;
    float rho = expf(lr[0]);
    float abR = 0.f, abI = 0.f;
    for (int k = 0; k < 64; ++k) {
        float wr = zin[(b * 2 + 0) * 64 + k] - uin[(b * 2 + 0) * 64 + k];
        float wi = zin[(b * 2 + 1) * 64 + k] - uin[(b * 2 + 1) * 64 + k];
        float2 h = *(const float2*)(AAHT + ((size_t)k * 64 + m) * 2);  // AAH[m][k]
        abR += wr * h.x - wi * h.y;
        abI += wi * h.x + wr * h.y;
    }
    float gR = 0.f, gI = 0.f;
#pragma unroll
    for (int s = 0; s < NSG; ++s) {
        gR += Gpart[(size_t)s * 131072 + (size_t)b * 128 + m];
        gI += Gpart[(size_t)s * 131072 + (size_t)b * 128 + 64 + m];
    }
    abR = gR + rho * abR;
    abI = gI + rho * abI;
    AbS[w][m] = make_float2(abR, abI);
    __syncthreads();
    float tR = 0.f, tI = 0.f;
    for (int k = 0; k < 64; ++k) {
        float2 Wv = *(const float2*)(Wt + ((size_t)k * 64 + m) * 2);   // W[m][k]
        float2 ab = AbS[w][k];
        tR += ab.x * Wv.x - ab.y * Wv.y;
        tI += ab.y * Wv.x + ab.x * Wv.y;
    }
    float wr_m = zin[(b * 2 + 0) * 64 + m] - uin[(b * 2 + 0) * 64 + m];
    float wi_m = zin[(b * 2 + 1) * 64 + m] - uin[(b * 2 + 1) * 64 + m];
    q[(b * 2 + 0) * 64 + m] = rho * wr_m - tR;
    q[(b * 2 + 1) * 64 + m] = rho * wi_m - tI;
}

// ---------------------------------------------------------------------------
// xr[b][n] = relu( rn_r[b][n] + sum_m qr[m]*Ar[m][n] + qi[m]*Ai[m][n] )
// written into out's real rows: out[(2b)*N + n]
__global__ __launch_bounds__(256) void k_H2(const float* A, const float* rn,
                                            const float* q, float* xr) {
    int t = threadIdx.x;
    int n = blockIdx.x * 1024 + t * 4;
    int b0 = blockIdx.y * 16;
    const float* Ar = A;
    const float* Ai = A + (size_t)M_ * N_;
    float4 s[16];
#pragma unroll
    for (int b = 0; b < 16; ++b) s[b] = make_float4(0.f, 0.f, 0.f, 0.f);
    for (int mm = 0; mm < 64; ++mm) {
        float4 ar = *(const float4*)(Ar + (size_t)mm * N_ + n);
        float4 ai = *(const float4*)(Ai + (size_t)mm * N_ + n);
#pragma unroll
        for (int b = 0; b < 16; ++b) {
            float qr = q[((b0 + b) * 2 + 0) * 64 + mm];
            float qi = q[((b0 + b) * 2 + 1) * 64 + mm];
            s[b].x += qr * ar.x + qi * ai.x;
            s[b].y += qr * ar.y + qi * ai.y;
            s[b].z += qr * ar.z + qi * ai.z;
            s[b].w += qr * ar.w + qi * ai.w;
        }
    }
#pragma unroll
    for (int b = 0; b < 16; ++b) {
        float4 r = *(const float4*)(rn + (size_t)(b0 + b) * 2 * N_ + n);
        float4 o;
        o.x = fmaxf(r.x + s[b].x, 0.f);
        o.y = fmaxf(r.y + s[b].y, 0.f);
        o.z = fmaxf(r.z + s[b].z, 0.f);
        o.w = fmaxf(r.w + s[b].w, 0.f);
        *(float4*)(xr + (size_t)(b0 + b) * 2 * N_ + n) = o;
    }
}

// ---------------------------------------------------------------------------
// Axpart[split][b][c][m] : partials of Ax (x real only)
__global__ __launch_bounds__(256) void k_H3(const float* AT, const float* xr, float* Axpart) {
    __shared__ float redL[4][2048];
    int t = threadIdx.x;
    int m = t & 63;
    int w = __builtin_amdgcn_readfirstlane(t >> 6);
    int split = blockIdx.x;
    int b0 = blockIdx.y * 16;
    int n0 = split * 1024 + w * 256;
    float aR[16], aI[16];
#pragma unroll
    for (int b = 0; b < 16; ++b) { aR[b] = 0.f; aI[b] = 0.f; }
    for (int j = 0; j < 256; ++j) {
        int n = n0 + j;
        float2 a = *(const float2*)(AT + ((size_t)n * 64 + m) * 2);
#pragma unroll
        for (int b = 0; b < 16; ++b) {
            float x = xr[(size_t)(b0 + b) * 2 * N_ + n];
            aR[b] += x * a.x;
            aI[b] += x * a.y;
        }
    }
#pragma unroll
    for (int b = 0; b < 16; ++b) {
        redL[w][b * 128 + m] = aR[b];
        redL[w][b * 128 + 64 + m] = aI[b];
    }
    __syncthreads();
    for (int k = t; k < 2048; k += 256) {
        float s = redL[0][k] + redL[1][k] + redL[2][k] + redL[3][k];
        int bl = k >> 7, rem = k & 127;
        Axpart[(size_t)split * 131072 + (size_t)(b0 + bl) * 128 + rem] = s;
    }
}

// ---------------------------------------------------------------------------
// per-step epilogue: Ax = sum parts; v = Ax+u-y; z = y + v*min(1, eps/(nrm+1e-12));
// u = u + Ax - z.  Writes z,u (and u to out on last step).
__global__ __launch_bounds__(128) void k_small3(const float* Axpart, const float* uin,
                                                const float* y, const float* le,
                                                float* z, float* u, float* uout, int last) {
    __shared__ float red[2];
    int b = blockIdx.x, t = threadIdx.x;
    size_t idx = (size_t)b * 128 + t;
    float ax = 0.f;
#pragma unroll
    for (int s = 0; s < NS3; ++s) ax += Axpart[(size_t)s * 131072 + idx];
    float uo = uin[idx], yv = y[idx];
    float v = ax + uo - yv;
    float sq = v * v;
    for (int off = 32; off > 0; off >>= 1) sq += __shfl_down(sq, off, 64);
    if ((t & 63) == 0) red[t >> 6] = sq;
    __syncthreads();
    float tot = red[0] + red[1];
    float eps = expf(le[0]);
    float scale = fminf(1.f, eps / (sqrtf(tot) + 1e-12f));
    float zv = yv + v * scale;
    float un = uo + ax - zv;
    z[idx] = zv;
    u[idx] = un;
    if (last) uout[idx] = un;
}

// ---------------------------------------------------------------------------
extern "C" void kernel_launch(void* const* d_in, const int* in_sizes, int n_in,
                              void* d_out, int out_size, void* d_ws, size_t ws_size,
                              hipStream_t stream) {
    const float* rn  = (const float*)d_in[0];   // (B,2,N)
    const float* y   = (const float*)d_in[1];   // (B,2,M)
    const float* uin = (const float*)d_in[2];   // (B,2,M)
    const float* A   = (const float*)d_in[3];   // (2,M,N)
    const float* lr  = (const float*)d_in[4];   // log_rho
    const float* le  = (const float*)d_in[5];   // log_epsilon

    float* out = (float*)d_out;
    float* ws  = (float*)d_ws;

    float* AT     = ws;                      // N*M*2        = 1,048,576
    float* Gpart  = AT + 1048576;            // NSG*B*2*M    = 2,097,152
    float* Axpart = Gpart + 2097152;         // NS3*B*2*M    = 1,048,576
    float* S      = Axpart + 1048576;        // 8192
    float* AAHT   = S + 8192;                // 8192
    float* Wt     = AAHT + 8192;             // 8192
    float* z      = Wt + 8192;               // 131072
    float* u      = z + 131072;              // 131072
    float* q      = u + 131072;              // 131072
    float* uout   = out + (size_t)B_ * 2 * N_;

    k_zero_imag<<<dim3(8, B_), 256, 0, stream>>>(out);
    k_transpA<<<128, 256, 0, stream>>>(A, AT);
    k_Sbuild<<<64, 256, 0, stream>>>(A, lr, S, AAHT);
    k_invert<<<1, 256, 0, stream>>>(S, Wt);
    k_G<<<dim3(NSG, 64), 256, 0, stream>>>(AT, rn, Gpart);

    for (int step = 0; step < 3; ++step) {
        const float* zp = (step == 0) ? y   : z;
        const float* up = (step == 0) ? uin : u;
        k_small12<<<256, 256, 0, stream>>>(Gpart, AAHT, Wt, zp, up, lr, q);
        k_H2<<<dim3(8, 64), 256, 0, stream>>>(A, rn, q, out);
        k_H3<<<dim3(NS3, 64), 256, 0, stream>>>(AT, out, Axpart);
        k_small3<<<B_, 128, 0, stream>>>(Axpart, up, y, le, z, u, uout, step == 2 ? 1 : 0);
    }
}

// Round 2
// 1545.088 us; speedup vs baseline: 1.3832x; 1.3832x over previous
//
#include <hip/hip_runtime.h>

#define B_ 1024
#define M_ 64
#define N_ 8192
#define NSG 16   // n-splits for k_G   (range 512 each)
#define NS3 8    // n-splits for k_H3  (range 1024 each)

// ---------------------------------------------------------------------------
// zero the imaginary rows of out-x: out[(2b+1)*N + n] = 0
__global__ __launch_bounds__(256) void k_zero_imag(float* out) {
    int b = blockIdx.y;
    int n = (blockIdx.x * 256 + threadIdx.x) * 4;
    float4 z = make_float4(0.f, 0.f, 0.f, 0.f);
    *(float4*)(out + (size_t)(2 * b + 1) * N_ + n) = z;
}

// ---------------------------------------------------------------------------
// S = I/(rho+1e-12) + A A^H  (complex 64x64, Hermitian).
// One block per upper-triangle element (i<=j): flat 256-thread reduction over N.
// Writes S[i][j], S[j][i]=conj, AAHT[k][m] = AAH[m][k].
__global__ __launch_bounds__(256) void k_Sbuild(const float* A, const float* lr,
                                                float* S, float* AAHT) {
    __shared__ float redS[8];
    int bid = blockIdx.x;
    int i = 0, rem = bid;
    while (rem >= 64 - i) { rem -= 64 - i; ++i; }
    int j = i + rem;                       // i <= j
    int t = threadIdx.x;
    const float* Ar = A;
    const float* Ai = A + (size_t)M_ * N_;
    const float* ari = Ar + (size_t)i * N_;
    const float* aii = Ai + (size_t)i * N_;
    const float* arj = Ar + (size_t)j * N_;
    const float* aij = Ai + (size_t)j * N_;
    float aR = 0.f, aI = 0.f;
#pragma unroll
    for (int it = 0; it < 8; ++it) {
        int n = it * 1024 + t * 4;
        float4 xr = *(const float4*)(ari + n);
        float4 xi = *(const float4*)(aii + n);
        float4 br = *(const float4*)(arj + n);
        float4 bi = *(const float4*)(aij + n);
        aR += xr.x * br.x + xi.x * bi.x + xr.y * br.y + xi.y * bi.y
            + xr.z * br.z + xi.z * bi.z + xr.w * br.w + xi.w * bi.w;
        aI += xi.x * br.x - xr.x * bi.x + xi.y * br.y - xr.y * bi.y
            + xi.z * br.z - xr.z * bi.z + xi.w * br.w - xr.w * bi.w;
    }
    for (int off = 32; off > 0; off >>= 1) {
        aR += __shfl_down(aR, off, 64);
        aI += __shfl_down(aI, off, 64);
    }
    int lane = t & 63, w = t >> 6;
    if (lane == 0) { redS[w * 2] = aR; redS[w * 2 + 1] = aI; }
    __syncthreads();
    if (t == 0) {
        float R = redS[0] + redS[2] + redS[4] + redS[6];
        float I = redS[1] + redS[3] + redS[5] + redS[7];
        float inv_rho = 1.0f / (expf(lr[0]) + 1e-12f);
        float diag = (i == j) ? inv_rho : 0.f;
        // S[i][j] = (R, I)
        S[((size_t)i * 64 + j) * 2 + 0] = R + diag;
        S[((size_t)i * 64 + j) * 2 + 1] = I;
        // AAHT[k=j][m=i] = AAH[i][j]
        AAHT[((size_t)j * 64 + i) * 2 + 0] = R;
        AAHT[((size_t)j * 64 + i) * 2 + 1] = I;
        if (i != j) {
            // S[j][i] = conj = (R, -I)
            S[((size_t)j * 64 + i) * 2 + 0] = R;
            S[((size_t)j * 64 + i) * 2 + 1] = -I;
            // AAHT[k=i][m=j] = AAH[j][i] = (R, -I)
            AAHT[((size_t)i * 64 + j) * 2 + 0] = R;
            AAHT[((size_t)i * 64 + j) * 2 + 1] = -I;
        }
    }
}

// ---------------------------------------------------------------------------
// complex Gauss-Jordan inverse of S (Hermitian PD, 64x64). Wt[k][m] = (S^-1)[m][k]
__global__ __launch_bounds__(256) void k_invert(const float* S, float* Wt) {
    __shared__ float2 Mg[64][128];
    __shared__ float2 fv[64];
    __shared__ float2 pinv_s;
    int t = threadIdx.x;
    for (int idx = t; idx < 4096; idx += 256) {
        int i = idx >> 6, j = idx & 63;
        Mg[i][j] = ((const float2*)S)[idx];
        Mg[i][64 + j] = (i == j) ? make_float2(1.f, 0.f) : make_float2(0.f, 0.f);
    }
    __syncthreads();
    for (int k = 0; k < 64; ++k) {
        if (t == 0) {
            float2 p = Mg[k][k];
            float d = p.x * p.x + p.y * p.y;
            pinv_s = make_float2(p.x / d, -p.y / d);
        }
        __syncthreads();
        if (t < 128) {
            float2 pv = pinv_s;
            float2 a = Mg[k][t];
            Mg[k][t] = make_float2(a.x * pv.x - a.y * pv.y, a.x * pv.y + a.y * pv.x);
        } else if (t < 192) {
            int i = t - 128;
            fv[i] = (i == k) ? make_float2(0.f, 0.f) : Mg[i][k];
        }
        __syncthreads();
        for (int idx = t; idx < 8192; idx += 256) {
            int i = idx >> 7, c = idx & 127;
            if (i != k) {
                float2 f = fv[i], r = Mg[k][c], a = Mg[i][c];
                Mg[i][c] = make_float2(a.x - (f.x * r.x - f.y * r.y),
                                       a.y - (f.x * r.y + f.y * r.x));
            }
        }
        __syncthreads();
    }
    for (int idx = t; idx < 4096; idx += 256) {
        int k = idx >> 6, m = idx & 63;
        ((float2*)Wt)[idx] = Mg[m][64 + k];
    }
}

// ---------------------------------------------------------------------------
// A_T[n][m][c] = A[c][m][n]  (so lanes-over-m read coalesced float2)
__global__ __launch_bounds__(256) void k_transpA(const float* A, float* AT) {
    __shared__ float tile[128][65];
    int n0 = blockIdx.x * 64;
    int t = threadIdx.x;
    int nl = t % 64, r0 = t / 64;
    for (int it = 0; it < 32; ++it) {
        int row = r0 + it * 4;                       // row = c*64+m
        tile[row][nl] = A[(size_t)row * N_ + n0 + nl];
    }
    __syncthreads();
    int j = t % 128, nn0 = t / 128;
    for (int it = 0; it < 32; ++it) {
        int nn = nn0 + it * 2;
        int m = j >> 1, c = j & 1;
        AT[((size_t)(n0 + nn) * 64 + m) * 2 + c] = tile[c * 64 + m][nn];
    }
}

// ---------------------------------------------------------------------------
// Gpart[split][b][c][m] : partial of G = A * r_n (complex), reduced over n-split
__global__ __launch_bounds__(256) void k_G(const float* AT, const float* rn, float* Gpart) {
    __shared__ float redL[4][2048];
    int t = threadIdx.x;
    int m = t & 63;
    int w = __builtin_amdgcn_readfirstlane(t >> 6);
    int split = blockIdx.x;
    int b0 = blockIdx.y * 16;
    int n0 = split * 512 + w * 128;
    float accR[16], accI[16];
#pragma unroll
    for (int b = 0; b < 16; ++b) { accR[b] = 0.f; accI[b] = 0.f; }
    for (int j = 0; j < 128; ++j) {
        int n = n0 + j;
        float2 a = *(const float2*)(AT + ((size_t)n * 64 + m) * 2);
#pragma unroll
        for (int b = 0; b < 16; ++b) {
            float rr = rn[((size_t)(b0 + b) * 2 + 0) * N_ + n];
            float ri = rn[((size_t)(b0 + b) * 2 + 1) * N_ + n];
            accR[b] += rr * a.x - ri * a.y;
            accI[b] += ri * a.x + rr * a.y;
        }
    }
#pragma unroll
    for (int b = 0; b < 16; ++b) {
        redL[w][b * 128 + m] = accR[b];
        redL[w][b * 128 + 64 + m] = accI[b];
    }
    __syncthreads();
    for (int k = t; k < 2048; k += 256) {
        float s = redL[0][k] + redL[1][k] + redL[2][k] + redL[3][k];
        int bl = k >> 7, rem = k & 127;
        Gpart[(size_t)split * 131072 + (size_t)(b0 + bl) * 128 + rem] = s;
    }
}

// ---------------------------------------------------------------------------
// per-step small: Ab = sum(Gpart) + rho*AAH*(z-u);  q = rho*(z-u) - S^-1*Ab
__global__ __launch_bounds__(256) void k_small12(const float* Gpart, const float* AAHT,
                                                 const float* Wt, const float* zin,
                                                 const float* uin, const float* lr, float* q) {
    __shared__ float2 AbS[4][64];
    int t = threadIdx.x;
    int m = t & 63;
    int w = __builtin_amdgcn_readfirstlane(t >> 6);
    int b = blockIdx.x * 4 + w;
    float rho = expf(lr[0]);
    float abR = 0.f, abI = 0.f;
    for (int k = 0; k < 64; ++k) {
        float wr = zin[(b * 2 + 0) * 64 + k] - uin[(b * 2 + 0) * 64 + k];
        float wi = zin[(b * 2 + 1) * 64 + k] - uin[(b * 2 + 1) * 64 + k];
        float2 h = *(const float2*)(AAHT + ((size_t)k * 64 + m) * 2);  // AAH[m][k]
        abR += wr * h.x - wi * h.y;
        abI += wi * h.x + wr * h.y;
    }
    float gR = 0.f, gI = 0.f;
#pragma unroll
    for (int s = 0; s < NSG; ++s) {
        gR += Gpart[(size_t)s * 131072 + (size_t)b * 128 + m];
        gI += Gpart[(size_t)s * 131072 + (size_t)b * 128 + 64 + m];
    }
    abR = gR + rho * abR;
    abI = gI + rho * abI;
    AbS[w][m] = make_float2(abR, abI);
    __syncthreads();
    float tR = 0.f, tI = 0.f;
    for (int k = 0; k < 64; ++k) {
        float2 Wv = *(const float2*)(Wt + ((size_t)k * 64 + m) * 2);   // W[m][k]
        float2 ab = AbS[w][k];
        tR += ab.x * Wv.x - ab.y * Wv.y;
        tI += ab.y * Wv.x + ab.x * Wv.y;
    }
    float wr_m = zin[(b * 2 + 0) * 64 + m] - uin[(b * 2 + 0) * 64 + m];
    float wi_m = zin[(b * 2 + 1) * 64 + m] - uin[(b * 2 + 1) * 64 + m];
    q[(b * 2 + 0) * 64 + m] = rho * wr_m - tR;
    q[(b * 2 + 1) * 64 + m] = rho * wi_m - tI;
}

// ---------------------------------------------------------------------------
// xr[b][n] = relu( rn_r[b][n] + sum_m qr[m]*Ar[m][n] + qi[m]*Ai[m][n] )
// written into out's real rows: out[(2b)*N + n]
__global__ __launch_bounds__(256) void k_H2(const float* A, const float* rn,
                                            const float* q, float* xr) {
    int t = threadIdx.x;
    int n = blockIdx.x * 1024 + t * 4;
    int b0 = blockIdx.y * 16;
    const float* Ar = A;
    const float* Ai = A + (size_t)M_ * N_;
    float4 s[16];
#pragma unroll
    for (int b = 0; b < 16; ++b) s[b] = make_float4(0.f, 0.f, 0.f, 0.f);
    for (int mm = 0; mm < 64; ++mm) {
        float4 ar = *(const float4*)(Ar + (size_t)mm * N_ + n);
        float4 ai = *(const float4*)(Ai + (size_t)mm * N_ + n);
#pragma unroll
        for (int b = 0; b < 16; ++b) {
            float qr = q[((b0 + b) * 2 + 0) * 64 + mm];
            float qi = q[((b0 + b) * 2 + 1) * 64 + mm];
            s[b].x += qr * ar.x + qi * ai.x;
            s[b].y += qr * ar.y + qi * ai.y;
            s[b].z += qr * ar.z + qi * ai.z;
            s[b].w += qr * ar.w + qi * ai.w;
        }
    }
#pragma unroll
    for (int b = 0; b < 16; ++b) {
        float4 r = *(const float4*)(rn + (size_t)(b0 + b) * 2 * N_ + n);
        float4 o;
        o.x = fmaxf(r.x + s[b].x, 0.f);
        o.y = fmaxf(r.y + s[b].y, 0.f);
        o.z = fmaxf(r.z + s[b].z, 0.f);
        o.w = fmaxf(r.w + s[b].w, 0.f);
        *(float4*)(xr + (size_t)(b0 + b) * 2 * N_ + n) = o;
    }
}

// ---------------------------------------------------------------------------
// Axpart[split][b][c][m] : partials of Ax (x real only)
__global__ __launch_bounds__(256) void k_H3(const float* AT, const float* xr, float* Axpart) {
    __shared__ float redL[4][2048];
    int t = threadIdx.x;
    int m = t & 63;
    int w = __builtin_amdgcn_readfirstlane(t >> 6);
    int split = blockIdx.x;
    int b0 = blockIdx.y * 16;
    int n0 = split * 1024 + w * 256;
    float aR[16], aI[16];
#pragma unroll
    for (int b = 0; b < 16; ++b) { aR[b] = 0.f; aI[b] = 0.f; }
    for (int j = 0; j < 256; ++j) {
        int n = n0 + j;
        float2 a = *(const float2*)(AT + ((size_t)n * 64 + m) * 2);
#pragma unroll
        for (int b = 0; b < 16; ++b) {
            float x = xr[(size_t)(b0 + b) * 2 * N_ + n];
            aR[b] += x * a.x;
            aI[b] += x * a.y;
        }
    }
#pragma unroll
    for (int b = 0; b < 16; ++b) {
        redL[w][b * 128 + m] = aR[b];
        redL[w][b * 128 + 64 + m] = aI[b];
    }
    __syncthreads();
    for (int k = t; k < 2048; k += 256) {
        float s = redL[0][k] + redL[1][k] + redL[2][k] + redL[3][k];
        int bl = k >> 7, rem = k & 127;
        Axpart[(size_t)split * 131072 + (size_t)(b0 + bl) * 128 + rem] = s;
    }
}

// ---------------------------------------------------------------------------
// per-step epilogue: Ax = sum parts; v = Ax+u-y; z = y + v*min(1, eps/(nrm+1e-12));
// u = u + Ax - z.  Writes z,u (and u to out on last step).
__global__ __launch_bounds__(128) void k_small3(const float* Axpart, const float* uin,
                                                const float* y, const float* le,
                                                float* z, float* u, float* uout, int last) {
    __shared__ float red[2];
    int b = blockIdx.x, t = threadIdx.x;
    size_t idx = (size_t)b * 128 + t;
    float ax = 0.f;
#pragma unroll
    for (int s = 0; s < NS3; ++s) ax += Axpart[(size_t)s * 131072 + idx];
    float uo = uin[idx], yv = y[idx];
    float v = ax + uo - yv;
    float sq = v * v;
    for (int off = 32; off > 0; off >>= 1) sq += __shfl_down(sq, off, 64);
    if ((t & 63) == 0) red[t >> 6] = sq;
    __syncthreads();
    float tot = red[0] + red[1];
    float eps = expf(le[0]);
    float scale = fminf(1.f, eps / (sqrtf(tot) + 1e-12f));
    float zv = yv + v * scale;
    float un = uo + ax - zv;
    z[idx] = zv;
    u[idx] = un;
    if (last) uout[idx] = un;
}

// ---------------------------------------------------------------------------
extern "C" void kernel_launch(void* const* d_in, const int* in_sizes, int n_in,
                              void* d_out, int out_size, void* d_ws, size_t ws_size,
                              hipStream_t stream) {
    const float* rn  = (const float*)d_in[0];   // (B,2,N)
    const float* y   = (const float*)d_in[1];   // (B,2,M)
    const float* uin = (const float*)d_in[2];   // (B,2,M)
    const float* A   = (const float*)d_in[3];   // (2,M,N)
    const float* lr  = (const float*)d_in[4];   // log_rho
    const float* le  = (const float*)d_in[5];   // log_epsilon

    float* out = (float*)d_out;
    float* ws  = (float*)d_ws;

    float* AT     = ws;                      // N*M*2        = 1,048,576
    float* Gpart  = AT + 1048576;            // NSG*B*2*M    = 2,097,152
    float* Axpart = Gpart + 2097152;         // NS3*B*2*M    = 1,048,576
    float* S      = Axpart + 1048576;        // 8192
    float* AAHT   = S + 8192;                // 8192
    float* Wt     = AAHT + 8192;             // 8192
    float* z      = Wt + 8192;               // 131072
    float* u      = z + 131072;              // 131072
    float* q      = u + 131072;              // 131072
    float* uout   = out + (size_t)B_ * 2 * N_;

    k_zero_imag<<<dim3(8, B_), 256, 0, stream>>>(out);
    k_transpA<<<128, 256, 0, stream>>>(A, AT);
    k_Sbuild<<<2080, 256, 0, stream>>>(A, lr, S, AAHT);
    k_invert<<<1, 256, 0, stream>>>(S, Wt);
    k_G<<<dim3(NSG, 64), 256, 0, stream>>>(AT, rn, Gpart);

    for (int step = 0; step < 3; ++step) {
        const float* zp = (step == 0) ? y   : z;
        const float* up = (step == 0) ? uin : u;
        k_small12<<<256, 256, 0, stream>>>(Gpart, AAHT, Wt, zp, up, lr, q);
        k_H2<<<dim3(8, 64), 256, 0, stream>>>(A, rn, q, out);
        k_H3<<<dim3(NS3, 64), 256, 0, stream>>>(AT, out, Axpart);
        k_small3<<<B_, 128, 0, stream>>>(Axpart, up, y, le, z, u, uout, step == 2 ? 1 : 0);
    }
}

// Round 3
// 617.525 us; speedup vs baseline: 3.4609x; 2.5021x over previous
//
#include <hip/hip_runtime.h>

#define B_ 1024
#define M_ 64
#define N_ 8192
#define NSG 32   // k-splits for k_G  (chunk 512 of K=16384)
#define NS3 16   // k-splits for k_H3 (chunk 512 of K=8192)

typedef __attribute__((ext_vector_type(8))) short bf16x8;
typedef __attribute__((ext_vector_type(4))) float f32x4;

__device__ inline unsigned short f2b(float f) {
    union { float f; unsigned u; } v; v.f = f;
    unsigned r = v.u + 0x7FFFu + ((v.u >> 16) & 1u);
    return (unsigned short)(r >> 16);
}
__device__ inline unsigned rne2(float lo, float hi) {
    union { float f; unsigned u; } a, b; a.f = lo; b.f = hi;
    unsigned x = (a.u + 0x7FFFu + ((a.u >> 16) & 1u)) >> 16;
    unsigned y = (b.u + 0x7FFFu + ((b.u >> 16) & 1u)) >> 16;
    return x | (y << 16);
}
__device__ inline bf16x8 cvt8(const float* p) {
    float4 f0 = *(const float4*)p;
    float4 f1 = *(const float4*)(p + 4);
    union { bf16x8 v; unsigned u[4]; } r;
    r.u[0] = rne2(f0.x, f0.y); r.u[1] = rne2(f0.z, f0.w);
    r.u[2] = rne2(f1.x, f1.y); r.u[3] = rne2(f1.z, f1.w);
    return r.v;
}

// ---------------------------------------------------------------------------
// zero the imaginary rows of out-x: out[(2b+1)*N + n] = 0
__global__ __launch_bounds__(256) void k_zero_imag(float* out) {
    int b = blockIdx.y;
    int n = (blockIdx.x * 256 + threadIdx.x) * 4;
    float4 z = make_float4(0.f, 0.f, 0.f, 0.f);
    *(float4*)(out + (size_t)(2 * b + 1) * N_ + n) = z;
}

// ---------------------------------------------------------------------------
// Abf = bf16(A) flat (2*64*8192)
__global__ __launch_bounds__(256) void k_cvtA(const float* A, unsigned short* Abf) {
    size_t i = ((size_t)blockIdx.x * 256 + threadIdx.x) * 8;
    float4 f0 = *(const float4*)(A + i);
    float4 f1 = *(const float4*)(A + i + 4);
    union { bf16x8 v; unsigned u[4]; } r;
    r.u[0] = rne2(f0.x, f0.y); r.u[1] = rne2(f0.z, f0.w);
    r.u[2] = rne2(f1.x, f1.y); r.u[3] = rne2(f1.z, f1.w);
    *(bf16x8*)(Abf + i) = r.v;
}

// ---------------------------------------------------------------------------
// WgT[o][k] bf16, o=0..127 (c_out*64+m), k=0..16383 (c_in*8192+n)
// o<64 : [ Ar[m] | -Ai[m] ] ;  o>=64 : [ Ai[m] | Ar[m] ]
__global__ __launch_bounds__(256) void k_prep_wg(const float* A, unsigned short* WgT) {
    int o = blockIdx.x;
    int kb = blockIdx.y * 2048 + threadIdx.x * 8;
    int m = o & 63;
    const float* Ar = A + (size_t)m * N_;
    const float* Ai = A + (size_t)M_ * N_ + (size_t)m * N_;
    bool oimag = o >= 64;
    bool khigh = kb >= N_;
    int koff = khigh ? kb - N_ : kb;
    const float* src = oimag ? (khigh ? Ar : Ai) : (khigh ? Ai : Ar);
    float sgn = (!oimag && khigh) ? -1.f : 1.f;
    float4 f0 = *(const float4*)(src + koff);
    float4 f1 = *(const float4*)(src + koff + 4);
    union { bf16x8 v; unsigned u[4]; } r;
    r.u[0] = rne2(sgn * f0.x, sgn * f0.y); r.u[1] = rne2(sgn * f0.z, sgn * f0.w);
    r.u[2] = rne2(sgn * f1.x, sgn * f1.y); r.u[3] = rne2(sgn * f1.z, sgn * f1.w);
    *(bf16x8*)(WgT + (size_t)o * 16384 + kb) = r.v;
}

// ---------------------------------------------------------------------------
// ATb[n][k] bf16, k = c*64+m : ATb[n][c*64+m] = A[c][m][n]
__global__ __launch_bounds__(256) void k_transpA(const float* A, unsigned short* ATb) {
    __shared__ float tile[128][65];
    int n0 = blockIdx.x * 64;
    int t = threadIdx.x;
    int nl = t % 64, r0 = t / 64;
    for (int it = 0; it < 32; ++it) {
        int row = r0 + it * 4;                       // row = c*64+m
        tile[row][nl] = A[(size_t)row * N_ + n0 + nl];
    }
    __syncthreads();
    int o = t % 128, nn0 = t / 128;
    for (int it = 0; it < 32; ++it) {
        int nn = nn0 + it * 2;
        ATb[(size_t)(n0 + nn) * 128 + o] = f2b(tile[o][nn]);
    }
}

// ---------------------------------------------------------------------------
// S = I/(rho+1e-12) + A A^H  (complex 64x64, Hermitian). fp32, unchanged.
__global__ __launch_bounds__(256) void k_Sbuild(const float* A, const float* lr,
                                                float* S, float* AAHT) {
    __shared__ float redS[8];
    int bid = blockIdx.x;
    int i = 0, rem = bid;
    while (rem >= 64 - i) { rem -= 64 - i; ++i; }
    int j = i + rem;                       // i <= j
    int t = threadIdx.x;
    const float* Ar = A;
    const float* Ai = A + (size_t)M_ * N_;
    const float* ari = Ar + (size_t)i * N_;
    const float* aii = Ai + (size_t)i * N_;
    const float* arj = Ar + (size_t)j * N_;
    const float* aij = Ai + (size_t)j * N_;
    float aR = 0.f, aI = 0.f;
#pragma unroll
    for (int it = 0; it < 8; ++it) {
        int n = it * 1024 + t * 4;
        float4 xr = *(const float4*)(ari + n);
        float4 xi = *(const float4*)(aii + n);
        float4 br = *(const float4*)(arj + n);
        float4 bi = *(const float4*)(aij + n);
        aR += xr.x * br.x + xi.x * bi.x + xr.y * br.y + xi.y * bi.y
            + xr.z * br.z + xi.z * bi.z + xr.w * br.w + xi.w * bi.w;
        aI += xi.x * br.x - xr.x * bi.x + xi.y * br.y - xr.y * bi.y
            + xi.z * br.z - xr.z * bi.z + xi.w * br.w - xr.w * bi.w;
    }
    for (int off = 32; off > 0; off >>= 1) {
        aR += __shfl_down(aR, off, 64);
        aI += __shfl_down(aI, off, 64);
    }
    int lane = t & 63, w = t >> 6;
    if (lane == 0) { redS[w * 2] = aR; redS[w * 2 + 1] = aI; }
    __syncthreads();
    if (t == 0) {
        float R = redS[0] + redS[2] + redS[4] + redS[6];
        float I = redS[1] + redS[3] + redS[5] + redS[7];
        float inv_rho = 1.0f / (expf(lr[0]) + 1e-12f);
        float diag = (i == j) ? inv_rho : 0.f;
        S[((size_t)i * 64 + j) * 2 + 0] = R + diag;
        S[((size_t)i * 64 + j) * 2 + 1] = I;
        AAHT[((size_t)j * 64 + i) * 2 + 0] = R;
        AAHT[((size_t)j * 64 + i) * 2 + 1] = I;
        if (i != j) {
            S[((size_t)j * 64 + i) * 2 + 0] = R;
            S[((size_t)j * 64 + i) * 2 + 1] = -I;
            AAHT[((size_t)i * 64 + j) * 2 + 0] = R;
            AAHT[((size_t)i * 64 + j) * 2 + 1] = -I;
        }
    }
}

// ---------------------------------------------------------------------------
// complex Gauss-Jordan inverse of S (64x64). Wt[k][m] = (S^-1)[m][k]
__global__ __launch_bounds__(256) void k_invert(const float* S, float* Wt) {
    __shared__ float2 Mg[64][128];
    __shared__ float2 fv[64];
    __shared__ float2 pinv_s;
    int t = threadIdx.x;
    for (int idx = t; idx < 4096; idx += 256) {
        int i = idx >> 6, j = idx & 63;
        Mg[i][j] = ((const float2*)S)[idx];
        Mg[i][64 + j] = (i == j) ? make_float2(1.f, 0.f) : make_float2(0.f, 0.f);
    }
    __syncthreads();
    for (int k = 0; k < 64; ++k) {
        if (t == 0) {
            float2 p = Mg[k][k];
            float d = p.x * p.x + p.y * p.y;
            pinv_s = make_float2(p.x / d, -p.y / d);
        }
        __syncthreads();
        if (t < 128) {
            float2 pv = pinv_s;
            float2 a = Mg[k][t];
            Mg[k][t] = make_float2(a.x * pv.x - a.y * pv.y, a.x * pv.y + a.y * pv.x);
        } else if (t < 192) {
            int i = t - 128;
            fv[i] = (i == k) ? make_float2(0.f, 0.f) : Mg[i][k];
        }
        __syncthreads();
        for (int idx = t; idx < 8192; idx += 256) {
            int i = idx >> 7, c = idx & 127;
            if (i != k) {
                float2 f = fv[i], r = Mg[k][c], a = Mg[i][c];
                Mg[i][c] = make_float2(a.x - (f.x * r.x - f.y * r.y),
                                       a.y - (f.x * r.y + f.y * r.x));
            }
        }
        __syncthreads();
    }
    for (int idx = t; idx < 4096; idx += 256) {
        int k = idx >> 6, m = idx & 63;
        ((float2*)Wt)[idx] = Mg[m][64 + k];
    }
}

// ---------------------------------------------------------------------------
// k_G: Gpart[split][b][o] = sum_{k in chunk} rn[b][k] * WgT[o][k]   (MFMA bf16)
// grid (NSG, 32 b-tiles of 32), 256 thr. wave w owns o-range w*32 (2 tiles).
__global__ __launch_bounds__(256) void k_G(const float* rn, const unsigned short* WgT,
                                           float* Gpart) {
    int t = threadIdx.x;
    int lane = t & 63;
    int w = t >> 6;
    int l15 = lane & 15;
    int q8 = (lane >> 4) * 8;
    int split = blockIdx.x;
    int b0 = blockIdx.y * 32;
    int k0 = split * 512;
    f32x4 a00 = {}, a01 = {}, a10 = {}, a11 = {};
    const float* x0 = rn + (size_t)(b0 + l15) * 16384 + k0 + q8;
    const float* x1 = x0 + (size_t)16 * 16384;
    const unsigned short* w0 = WgT + (size_t)(w * 32 + l15) * 16384 + k0 + q8;
    const unsigned short* w1 = w0 + (size_t)16 * 16384;
#pragma unroll 4
    for (int ks = 0; ks < 16; ++ks) {
        int kk = ks * 32;
        bf16x8 af0 = cvt8(x0 + kk);
        bf16x8 af1 = cvt8(x1 + kk);
        bf16x8 bf0 = *(const bf16x8*)(w0 + kk);
        bf16x8 bf1 = *(const bf16x8*)(w1 + kk);
        a00 = __builtin_amdgcn_mfma_f32_16x16x32_bf16(af0, bf0, a00, 0, 0, 0);
        a01 = __builtin_amdgcn_mfma_f32_16x16x32_bf16(af0, bf1, a01, 0, 0, 0);
        a10 = __builtin_amdgcn_mfma_f32_16x16x32_bf16(af1, bf0, a10, 0, 0, 0);
        a11 = __builtin_amdgcn_mfma_f32_16x16x32_bf16(af1, bf1, a11, 0, 0, 0);
    }
    int row = (lane >> 4) * 4;
    size_t base = (size_t)split * (B_ * 128);
    float* g00 = Gpart + base + (size_t)(b0 + row) * 128 + w * 32 + l15;
    float* g10 = Gpart + base + (size_t)(b0 + 16 + row) * 128 + w * 32 + l15;
#pragma unroll
    for (int r = 0; r < 4; ++r) {
        g00[(size_t)r * 128] = a00[r];
        g00[(size_t)r * 128 + 16] = a01[r];
        g10[(size_t)r * 128] = a10[r];
        g10[(size_t)r * 128 + 16] = a11[r];
    }
}

// ---------------------------------------------------------------------------
// per-step small: Ab = sum(Gpart) + rho*AAH*(z-u);  qb = bf16(rho*(z-u) - S^-1*Ab)
__global__ __launch_bounds__(256) void k_small12(const float* Gpart, const float* AAHT,
                                                 const float* Wt, const float* zin,
                                                 const float* uin, const float* lr,
                                                 unsigned short* qb) {
    __shared__ float2 AbS[4][64];
    int t = threadIdx.x;
    int m = t & 63;
    int w = __builtin_amdgcn_readfirstlane(t >> 6);
    int b = blockIdx.x * 4 + w;
    float rho = expf(lr[0]);
    float abR = 0.f, abI = 0.f;
    for (int k = 0; k < 64; ++k) {
        float wr = zin[(b * 2 + 0) * 64 + k] - uin[(b * 2 + 0) * 64 + k];
        float wi = zin[(b * 2 + 1) * 64 + k] - uin[(b * 2 + 1) * 64 + k];
        float2 h = *(const float2*)(AAHT + ((size_t)k * 64 + m) * 2);  // AAH[m][k]
        abR += wr * h.x - wi * h.y;
        abI += wi * h.x + wr * h.y;
    }
    float gR = 0.f, gI = 0.f;
#pragma unroll
    for (int s = 0; s < NSG; ++s) {
        gR += Gpart[(size_t)s * 131072 + (size_t)b * 128 + m];
        gI += Gpart[(size_t)s * 131072 + (size_t)b * 128 + 64 + m];
    }
    abR = gR + rho * abR;
    abI = gI + rho * abI;
    AbS[w][m] = make_float2(abR, abI);
    __syncthreads();
    float tR = 0.f, tI = 0.f;
    for (int k = 0; k < 64; ++k) {
        float2 Wv = *(const float2*)(Wt + ((size_t)k * 64 + m) * 2);   // W[m][k]
        float2 ab = AbS[w][k];
        tR += ab.x * Wv.x - ab.y * Wv.y;
        tI += ab.y * Wv.x + ab.x * Wv.y;
    }
    float wr_m = zin[(b * 2 + 0) * 64 + m] - uin[(b * 2 + 0) * 64 + m];
    float wi_m = zin[(b * 2 + 1) * 64 + m] - uin[(b * 2 + 1) * 64 + m];
    qb[(size_t)b * 128 + m] = f2b(rho * wr_m - tR);
    qb[(size_t)b * 128 + 64 + m] = f2b(rho * wi_m - tI);
}

// ---------------------------------------------------------------------------
// k_H2: x[b][n] = relu(rn_r[b][n] + sum_k qb[b][k]*ATb[n][k]), K=128 (MFMA)
// writes fp32 to out real rows + bf16 copy xb. grid (8 n-slabs, 64 b-tiles of 16)
__global__ __launch_bounds__(256) void k_H2(const unsigned short* qb, const unsigned short* ATb,
                                            const float* rn, float* out, unsigned short* xb) {
    int t = threadIdx.x;
    int lane = t & 63;
    int w = t >> 6;
    int l15 = lane & 15;
    int q8 = (lane >> 4) * 8;
    int b0 = blockIdx.y * 16;
    int n0 = blockIdx.x * 1024 + w * 256;
    bf16x8 a[4];
    const unsigned short* qrow = qb + (size_t)(b0 + l15) * 128 + q8;
#pragma unroll
    for (int ks = 0; ks < 4; ++ks) a[ks] = *(const bf16x8*)(qrow + ks * 32);
    int row = (lane >> 4) * 4;
#pragma unroll 2
    for (int nt = 0; nt < 16; ++nt) {
        f32x4 acc = {};
        const unsigned short* bbase = ATb + (size_t)(n0 + nt * 16 + l15) * 128 + q8;
#pragma unroll
        for (int ks = 0; ks < 4; ++ks) {
            bf16x8 bf = *(const bf16x8*)(bbase + ks * 32);
            acc = __builtin_amdgcn_mfma_f32_16x16x32_bf16(a[ks], bf, acc, 0, 0, 0);
        }
        int ncol = n0 + nt * 16 + l15;
        int brow = b0 + row;
#pragma unroll
        for (int r = 0; r < 4; ++r) {
            size_t ridx = (size_t)(brow + r) * 16384 + ncol;   // real row of rn/out
            float v = acc[r] + rn[ridx];
            v = fmaxf(v, 0.f);
            out[ridx] = v;
            xb[(size_t)(brow + r) * 8192 + ncol] = f2b(v);
        }
    }
}

// ---------------------------------------------------------------------------
// k_H3: Axpart[split][b][o] = sum_{k in chunk} xb[b][k]*Abf[o][k]  (MFMA)
// grid (NS3, 32 b-tiles of 32)
__global__ __launch_bounds__(256) void k_H3(const unsigned short* xb, const unsigned short* Abf,
                                            float* Axpart) {
    int t = threadIdx.x;
    int lane = t & 63;
    int w = t >> 6;
    int l15 = lane & 15;
    int q8 = (lane >> 4) * 8;
    int split = blockIdx.x;
    int b0 = blockIdx.y * 32;
    int k0 = split * 512;
    f32x4 a00 = {}, a01 = {}, a10 = {}, a11 = {};
    const unsigned short* x0 = xb + (size_t)(b0 + l15) * 8192 + k0 + q8;
    const unsigned short* x1 = x0 + (size_t)16 * 8192;
    const unsigned short* w0 = Abf + (size_t)(w * 32 + l15) * 8192 + k0 + q8;
    const unsigned short* w1 = w0 + (size_t)16 * 8192;
#pragma unroll 4
    for (int ks = 0; ks < 16; ++ks) {
        int kk = ks * 32;
        bf16x8 af0 = *(const bf16x8*)(x0 + kk);
        bf16x8 af1 = *(const bf16x8*)(x1 + kk);
        bf16x8 bf0 = *(const bf16x8*)(w0 + kk);
        bf16x8 bf1 = *(const bf16x8*)(w1 + kk);
        a00 = __builtin_amdgcn_mfma_f32_16x16x32_bf16(af0, bf0, a00, 0, 0, 0);
        a01 = __builtin_amdgcn_mfma_f32_16x16x32_bf16(af0, bf1, a01, 0, 0, 0);
        a10 = __builtin_amdgcn_mfma_f32_16x16x32_bf16(af1, bf0, a10, 0, 0, 0);
        a11 = __builtin_amdgcn_mfma_f32_16x16x32_bf16(af1, bf1, a11, 0, 0, 0);
    }
    int row = (lane >> 4) * 4;
    size_t base = (size_t)split * (B_ * 128);
    float* g00 = Axpart + base + (size_t)(b0 + row) * 128 + w * 32 + l15;
    float* g10 = Axpart + base + (size_t)(b0 + 16 + row) * 128 + w * 32 + l15;
#pragma unroll
    for (int r = 0; r < 4; ++r) {
        g00[(size_t)r * 128] = a00[r];
        g00[(size_t)r * 128 + 16] = a01[r];
        g10[(size_t)r * 128] = a10[r];
        g10[(size_t)r * 128 + 16] = a11[r];
    }
}

// ---------------------------------------------------------------------------
// per-step epilogue: Ax = sum parts; v = Ax+u-y; z = y + v*min(1, eps/(nrm+1e-12));
// u = u + Ax - z.  Writes z,u (and u to out on last step).
__global__ __launch_bounds__(128) void k_small3(const float* Axpart, const float* uin,
                                                const float* y, const float* le,
                                                float* z, float* u, float* uout, int last) {
    __shared__ float red[2];
    int b = blockIdx.x, t = threadIdx.x;
    size_t idx = (size_t)b * 128 + t;
    float ax = 0.f;
#pragma unroll
    for (int s = 0; s < NS3; ++s) ax += Axpart[(size_t)s * 131072 + idx];
    float uo = uin[idx], yv = y[idx];
    float v = ax + uo - yv;
    float sq = v * v;
    for (int off = 32; off > 0; off >>= 1) sq += __shfl_down(sq, off, 64);
    if ((t & 63) == 0) red[t >> 6] = sq;
    __syncthreads();
    float tot = red[0] + red[1];
    float eps = expf(le[0]);
    float scale = fminf(1.f, eps / (sqrtf(tot) + 1e-12f));
    float zv = yv + v * scale;
    float un = uo + ax - zv;
    z[idx] = zv;
    u[idx] = un;
    if (last) uout[idx] = un;
}

// ---------------------------------------------------------------------------
extern "C" void kernel_launch(void* const* d_in, const int* in_sizes, int n_in,
                              void* d_out, int out_size, void* d_ws, size_t ws_size,
                              hipStream_t stream) {
    const float* rn  = (const float*)d_in[0];   // (B,2,N)
    const float* y   = (const float*)d_in[1];   // (B,2,M)
    const float* uin = (const float*)d_in[2];   // (B,2,M)
    const float* A   = (const float*)d_in[3];   // (2,M,N)
    const float* lr  = (const float*)d_in[4];   // log_rho
    const float* le  = (const float*)d_in[5];   // log_epsilon

    float* out = (float*)d_out;
    float* ws  = (float*)d_ws;

    float* Gpart  = ws;                          // NSG*B*128      = 4,194,304 f
    float* Axpart = Gpart + (size_t)NSG * 131072;      // NS3*B*128 = 2,097,152 f
    float* S      = Axpart + (size_t)NS3 * 131072;     // 8192
    float* AAHT   = S + 8192;                    // 8192
    float* Wt     = AAHT + 8192;                 // 8192
    float* z      = Wt + 8192;                   // 131072
    float* u      = z + 131072;                  // 131072
    unsigned short* qb  = (unsigned short*)(u + 131072);   // 131072 us
    unsigned short* xb  = qb + 131072;           // B*N          = 8,388,608 us
    unsigned short* WgT = xb + (size_t)B_ * N_;  // 128*16384    = 2,097,152 us
    unsigned short* Abf = WgT + 2097152;         // 2*64*8192    = 1,048,576 us
    unsigned short* ATb = Abf + 1048576;         // 8192*128     = 1,048,576 us
    float* uout = out + (size_t)B_ * 2 * N_;

    k_zero_imag<<<dim3(8, B_), 256, 0, stream>>>(out);
    k_cvtA<<<512, 256, 0, stream>>>(A, Abf);
    k_prep_wg<<<dim3(128, 8), 256, 0, stream>>>(A, WgT);
    k_transpA<<<128, 256, 0, stream>>>(A, ATb);
    k_Sbuild<<<2080, 256, 0, stream>>>(A, lr, S, AAHT);
    k_invert<<<1, 256, 0, stream>>>(S, Wt);
    k_G<<<dim3(NSG, 32), 256, 0, stream>>>(rn, WgT, Gpart);

    for (int step = 0; step < 3; ++step) {
        const float* zp = (step == 0) ? y   : z;
        const float* up = (step == 0) ? uin : u;
        k_small12<<<256, 256, 0, stream>>>(Gpart, AAHT, Wt, zp, up, lr, qb);
        k_H2<<<dim3(8, 64), 256, 0, stream>>>(qb, ATb, rn, out, xb);
        k_H3<<<dim3(NS3, 32), 256, 0, stream>>>(xb, Abf, Axpart);
        k_small3<<<B_, 128, 0, stream>>>(Axpart, up, y, le, z, u, uout, step == 2 ? 1 : 0);
    }
}

// Round 4
// 538.337 us; speedup vs baseline: 3.9700x; 1.1471x over previous
//
#include <hip/hip_runtime.h>

#define B_ 1024
#define M_ 64
#define N_ 8192
#define NSG 32   // k-splits for k_G  (chunk 512 of K=16384)
#define NS3 16   // k-splits for k_H3 (chunk 512 of K=8192)

typedef __attribute__((ext_vector_type(8))) short bf16x8;
typedef __attribute__((ext_vector_type(4))) float f32x4;

__device__ inline unsigned short f2b(float f) {
    union { float f; unsigned u; } v; v.f = f;
    unsigned r = v.u + 0x7FFFu + ((v.u >> 16) & 1u);
    return (unsigned short)(r >> 16);
}
__device__ inline unsigned rne2(float lo, float hi) {
    union { float f; unsigned u; } a, b; a.f = lo; b.f = hi;
    unsigned x = (a.u + 0x7FFFu + ((a.u >> 16) & 1u)) >> 16;
    unsigned y = (b.u + 0x7FFFu + ((b.u >> 16) & 1u)) >> 16;
    return x | (y << 16);
}
__device__ inline bf16x8 cvt8(const float* p) {
    float4 f0 = *(const float4*)p;
    float4 f1 = *(const float4*)(p + 4);
    union { bf16x8 v; unsigned u[4]; } r;
    r.u[0] = rne2(f0.x, f0.y); r.u[1] = rne2(f0.z, f0.w);
    r.u[2] = rne2(f1.x, f1.y); r.u[3] = rne2(f1.z, f1.w);
    return r.v;
}

// ---------------------------------------------------------------------------
// zero the imaginary rows of out-x: out[(2b+1)*N + n] = 0
__global__ __launch_bounds__(256) void k_zero_imag(float* out) {
    int b = blockIdx.y;
    int n = (blockIdx.x * 256 + threadIdx.x) * 4;
    float4 z = make_float4(0.f, 0.f, 0.f, 0.f);
    *(float4*)(out + (size_t)(2 * b + 1) * N_ + n) = z;
}

// ---------------------------------------------------------------------------
// Abf = bf16(A) flat (2*64*8192)
__global__ __launch_bounds__(256) void k_cvtA(const float* A, unsigned short* Abf) {
    size_t i = ((size_t)blockIdx.x * 256 + threadIdx.x) * 8;
    float4 f0 = *(const float4*)(A + i);
    float4 f1 = *(const float4*)(A + i + 4);
    union { bf16x8 v; unsigned u[4]; } r;
    r.u[0] = rne2(f0.x, f0.y); r.u[1] = rne2(f0.z, f0.w);
    r.u[2] = rne2(f1.x, f1.y); r.u[3] = rne2(f1.z, f1.w);
    *(bf16x8*)(Abf + i) = r.v;
}

// ---------------------------------------------------------------------------
// WgT[o][k] bf16, o=0..127 (c_out*64+m), k=0..16383 (c_in*8192+n)
// o<64 : [ Ar[m] | -Ai[m] ] ;  o>=64 : [ Ai[m] | Ar[m] ]
__global__ __launch_bounds__(256) void k_prep_wg(const float* A, unsigned short* WgT) {
    int o = blockIdx.x;
    int kb = blockIdx.y * 2048 + threadIdx.x * 8;
    int m = o & 63;
    const float* Ar = A + (size_t)m * N_;
    const float* Ai = A + (size_t)M_ * N_ + (size_t)m * N_;
    bool oimag = o >= 64;
    bool khigh = kb >= N_;
    int koff = khigh ? kb - N_ : kb;
    const float* src = oimag ? (khigh ? Ar : Ai) : (khigh ? Ai : Ar);
    float sgn = (!oimag && khigh) ? -1.f : 1.f;
    float4 f0 = *(const float4*)(src + koff);
    float4 f1 = *(const float4*)(src + koff + 4);
    union { bf16x8 v; unsigned u[4]; } r;
    r.u[0] = rne2(sgn * f0.x, sgn * f0.y); r.u[1] = rne2(sgn * f0.z, sgn * f0.w);
    r.u[2] = rne2(sgn * f1.x, sgn * f1.y); r.u[3] = rne2(sgn * f1.z, sgn * f1.w);
    *(bf16x8*)(WgT + (size_t)o * 16384 + kb) = r.v;
}

// ---------------------------------------------------------------------------
// ATb[n][k] bf16, k = c*64+m : ATb[n][c*64+m] = A[c][m][n]
__global__ __launch_bounds__(256) void k_transpA(const float* A, unsigned short* ATb) {
    __shared__ float tile[128][65];
    int n0 = blockIdx.x * 64;
    int t = threadIdx.x;
    int nl = t % 64, r0 = t / 64;
    for (int it = 0; it < 32; ++it) {
        int row = r0 + it * 4;                       // row = c*64+m
        tile[row][nl] = A[(size_t)row * N_ + n0 + nl];
    }
    __syncthreads();
    int o = t % 128, nn0 = t / 128;
    for (int it = 0; it < 32; ++it) {
        int nn = nn0 + it * 2;
        ATb[(size_t)(n0 + nn) * 128 + o] = f2b(tile[o][nn]);
    }
}

// ---------------------------------------------------------------------------
// S = I/(rho+1e-12) + A A^H  (complex 64x64, Hermitian). fp32, unchanged.
__global__ __launch_bounds__(256) void k_Sbuild(const float* A, const float* lr,
                                                float* S, float* AAHT) {
    __shared__ float redS[8];
    int bid = blockIdx.x;
    int i = 0, rem = bid;
    while (rem >= 64 - i) { rem -= 64 - i; ++i; }
    int j = i + rem;                       // i <= j
    int t = threadIdx.x;
    const float* Ar = A;
    const float* Ai = A + (size_t)M_ * N_;
    const float* ari = Ar + (size_t)i * N_;
    const float* aii = Ai + (size_t)i * N_;
    const float* arj = Ar + (size_t)j * N_;
    const float* aij = Ai + (size_t)j * N_;
    float aR = 0.f, aI = 0.f;
#pragma unroll
    for (int it = 0; it < 8; ++it) {
        int n = it * 1024 + t * 4;
        float4 xr = *(const float4*)(ari + n);
        float4 xi = *(const float4*)(aii + n);
        float4 br = *(const float4*)(arj + n);
        float4 bi = *(const float4*)(aij + n);
        aR += xr.x * br.x + xi.x * bi.x + xr.y * br.y + xi.y * bi.y
            + xr.z * br.z + xi.z * bi.z + xr.w * br.w + xi.w * bi.w;
        aI += xi.x * br.x - xr.x * bi.x + xi.y * br.y - xr.y * bi.y
            + xi.z * br.z - xr.z * bi.z + xi.w * br.w - xr.w * bi.w;
    }
    for (int off = 32; off > 0; off >>= 1) {
        aR += __shfl_down(aR, off, 64);
        aI += __shfl_down(aI, off, 64);
    }
    int lane = t & 63, w = t >> 6;
    if (lane == 0) { redS[w * 2] = aR; redS[w * 2 + 1] = aI; }
    __syncthreads();
    if (t == 0) {
        float R = redS[0] + redS[2] + redS[4] + redS[6];
        float I = redS[1] + redS[3] + redS[5] + redS[7];
        float inv_rho = 1.0f / (expf(lr[0]) + 1e-12f);
        float diag = (i == j) ? inv_rho : 0.f;
        S[((size_t)i * 64 + j) * 2 + 0] = R + diag;
        S[((size_t)i * 64 + j) * 2 + 1] = I;
        AAHT[((size_t)j * 64 + i) * 2 + 0] = R;
        AAHT[((size_t)j * 64 + i) * 2 + 1] = I;
        if (i != j) {
            S[((size_t)j * 64 + i) * 2 + 0] = R;
            S[((size_t)j * 64 + i) * 2 + 1] = -I;
            AAHT[((size_t)i * 64 + j) * 2 + 0] = R;
            AAHT[((size_t)i * 64 + j) * 2 + 1] = -I;
        }
    }
}

// ---------------------------------------------------------------------------
// Register-resident complex Gauss-Jordan inverse (64x64, diag-dominant, no pivot).
// 16 waves; wave g owns 8-column group, lane i owns row i. Matrix in VGPRs.
// Pivot column via LDS (parity double-buffer, ONE barrier/iter); pivot row via shfl.
// Wt[k][m] = (S^-1)[m][k]
__global__ __launch_bounds__(1024) void k_invert(const float* S, float* Wt) {
    __shared__ float2 fvs[2][64];
    int t = threadIdx.x;
    int lane = t & 63;          // row i
    int g = t >> 6;             // column group
    float2 m[8];
#pragma unroll
    for (int j = 0; j < 8; ++j) {
        int c = g * 8 + j;
        if (c < 64) {
            m[j] = ((const float2*)S)[(size_t)lane * 64 + c];
        } else {
            m[j] = (lane == c - 64) ? make_float2(1.f, 0.f) : make_float2(0.f, 0.f);
        }
    }
    for (int k = 0; k < 64; ++k) {
        int kg = k >> 3, ke = k & 7, par = k & 1;
        if (g == kg) fvs[par][lane] = m[ke];   // publish pivot column (pre-update)
        __syncthreads();
        float2 f = fvs[par][lane];             // Mg[lane][k]
        float2 p = fvs[par][k];                // Mg[k][k]  (broadcast read)
        float d = p.x * p.x + p.y * p.y;
        float pix = p.x / d, piy = -p.y / d;   // 1/p
        bool isk = (lane == k);
#pragma unroll
        for (int j = 0; j < 8; ++j) {
            float prx = __shfl(m[j].x, k, 64);
            float pry = __shfl(m[j].y, k, 64);
            float srx = prx * pix - pry * piy; // scaled pivot row
            float sry = prx * piy + pry * pix;
            if (isk) {
                m[j] = make_float2(srx, sry);
            } else {
                m[j].x -= f.x * srx - f.y * sry;
                m[j].y -= f.x * sry + f.y * srx;
            }
        }
        // no trailing barrier: next iter writes fvs[1-par]; WAR separated by 2 barriers
    }
#pragma unroll
    for (int j = 0; j < 8; ++j) {
        int c = g * 8 + j;
        if (c >= 64) {
            ((float2*)Wt)[(size_t)(c - 64) * 64 + lane] = m[j];  // Wt[k][m=lane]
        }
    }
}

// ---------------------------------------------------------------------------
// k_G: Gpart[split][b][o] = sum_{k in chunk} rn[b][k] * WgT[o][k]   (MFMA bf16)
__global__ __launch_bounds__(256) void k_G(const float* rn, const unsigned short* WgT,
                                           float* Gpart) {
    int t = threadIdx.x;
    int lane = t & 63;
    int w = t >> 6;
    int l15 = lane & 15;
    int q8 = (lane >> 4) * 8;
    int split = blockIdx.x;
    int b0 = blockIdx.y * 32;
    int k0 = split * 512;
    f32x4 a00 = {}, a01 = {}, a10 = {}, a11 = {};
    const float* x0 = rn + (size_t)(b0 + l15) * 16384 + k0 + q8;
    const float* x1 = x0 + (size_t)16 * 16384;
    const unsigned short* w0 = WgT + (size_t)(w * 32 + l15) * 16384 + k0 + q8;
    const unsigned short* w1 = w0 + (size_t)16 * 16384;
#pragma unroll 4
    for (int ks = 0; ks < 16; ++ks) {
        int kk = ks * 32;
        bf16x8 af0 = cvt8(x0 + kk);
        bf16x8 af1 = cvt8(x1 + kk);
        bf16x8 bf0 = *(const bf16x8*)(w0 + kk);
        bf16x8 bf1 = *(const bf16x8*)(w1 + kk);
        a00 = __builtin_amdgcn_mfma_f32_16x16x32_bf16(af0, bf0, a00, 0, 0, 0);
        a01 = __builtin_amdgcn_mfma_f32_16x16x32_bf16(af0, bf1, a01, 0, 0, 0);
        a10 = __builtin_amdgcn_mfma_f32_16x16x32_bf16(af1, bf0, a10, 0, 0, 0);
        a11 = __builtin_amdgcn_mfma_f32_16x16x32_bf16(af1, bf1, a11, 0, 0, 0);
    }
    int row = (lane >> 4) * 4;
    size_t base = (size_t)split * (B_ * 128);
    float* g00 = Gpart + base + (size_t)(b0 + row) * 128 + w * 32 + l15;
    float* g10 = Gpart + base + (size_t)(b0 + 16 + row) * 128 + w * 32 + l15;
#pragma unroll
    for (int r = 0; r < 4; ++r) {
        g00[(size_t)r * 128] = a00[r];
        g00[(size_t)r * 128 + 16] = a01[r];
        g10[(size_t)r * 128] = a10[r];
        g10[(size_t)r * 128 + 16] = a11[r];
    }
}

// ---------------------------------------------------------------------------
// per-step small: Ab = sum(Gpart) + rho*AAH*(z-u);  qb = bf16(rho*(z-u) - S^-1*Ab)
__global__ __launch_bounds__(256) void k_small12(const float* Gpart, const float* AAHT,
                                                 const float* Wt, const float* zin,
                                                 const float* uin, const float* lr,
                                                 unsigned short* qb) {
    __shared__ float2 AbS[4][64];
    int t = threadIdx.x;
    int m = t & 63;
    int w = __builtin_amdgcn_readfirstlane(t >> 6);
    int b = blockIdx.x * 4 + w;
    float rho = expf(lr[0]);
    float abR = 0.f, abI = 0.f;
    for (int k = 0; k < 64; ++k) {
        float wr = zin[(b * 2 + 0) * 64 + k] - uin[(b * 2 + 0) * 64 + k];
        float wi = zin[(b * 2 + 1) * 64 + k] - uin[(b * 2 + 1) * 64 + k];
        float2 h = *(const float2*)(AAHT + ((size_t)k * 64 + m) * 2);  // AAH[m][k]
        abR += wr * h.x - wi * h.y;
        abI += wi * h.x + wr * h.y;
    }
    float gR = 0.f, gI = 0.f;
#pragma unroll
    for (int s = 0; s < NSG; ++s) {
        gR += Gpart[(size_t)s * 131072 + (size_t)b * 128 + m];
        gI += Gpart[(size_t)s * 131072 + (size_t)b * 128 + 64 + m];
    }
    abR = gR + rho * abR;
    abI = gI + rho * abI;
    AbS[w][m] = make_float2(abR, abI);
    __syncthreads();
    float tR = 0.f, tI = 0.f;
    for (int k = 0; k < 64; ++k) {
        float2 Wv = *(const float2*)(Wt + ((size_t)k * 64 + m) * 2);   // W[m][k]
        float2 ab = AbS[w][k];
        tR += ab.x * Wv.x - ab.y * Wv.y;
        tI += ab.y * Wv.x + ab.x * Wv.y;
    }
    float wr_m = zin[(b * 2 + 0) * 64 + m] - uin[(b * 2 + 0) * 64 + m];
    float wi_m = zin[(b * 2 + 1) * 64 + m] - uin[(b * 2 + 1) * 64 + m];
    qb[(size_t)b * 128 + m] = f2b(rho * wr_m - tR);
    qb[(size_t)b * 128 + 64 + m] = f2b(rho * wi_m - tI);
}

// ---------------------------------------------------------------------------
// k_H2: x[b][n] = relu(rn_r[b][n] + sum_k qb[b][k]*ATb[n][k]), K=128 (MFMA)
__global__ __launch_bounds__(256) void k_H2(const unsigned short* qb, const unsigned short* ATb,
                                            const float* rn, float* out, unsigned short* xb) {
    int t = threadIdx.x;
    int lane = t & 63;
    int w = t >> 6;
    int l15 = lane & 15;
    int q8 = (lane >> 4) * 8;
    int b0 = blockIdx.y * 16;
    int n0 = blockIdx.x * 1024 + w * 256;
    bf16x8 a[4];
    const unsigned short* qrow = qb + (size_t)(b0 + l15) * 128 + q8;
#pragma unroll
    for (int ks = 0; ks < 4; ++ks) a[ks] = *(const bf16x8*)(qrow + ks * 32);
    int row = (lane >> 4) * 4;
#pragma unroll 2
    for (int nt = 0; nt < 16; ++nt) {
        f32x4 acc = {};
        const unsigned short* bbase = ATb + (size_t)(n0 + nt * 16 + l15) * 128 + q8;
#pragma unroll
        for (int ks = 0; ks < 4; ++ks) {
            bf16x8 bf = *(const bf16x8*)(bbase + ks * 32);
            acc = __builtin_amdgcn_mfma_f32_16x16x32_bf16(a[ks], bf, acc, 0, 0, 0);
        }
        int ncol = n0 + nt * 16 + l15;
        int brow = b0 + row;
#pragma unroll
        for (int r = 0; r < 4; ++r) {
            size_t ridx = (size_t)(brow + r) * 16384 + ncol;   // real row of rn/out
            float v = acc[r] + rn[ridx];
            v = fmaxf(v, 0.f);
            out[ridx] = v;
            xb[(size_t)(brow + r) * 8192 + ncol] = f2b(v);
        }
    }
}

// ---------------------------------------------------------------------------
// k_H3: Axpart[split][b][o] = sum_{k in chunk} xb[b][k]*Abf[o][k]  (MFMA)
__global__ __launch_bounds__(256) void k_H3(const unsigned short* xb, const unsigned short* Abf,
                                            float* Axpart) {
    int t = threadIdx.x;
    int lane = t & 63;
    int w = t >> 6;
    int l15 = lane & 15;
    int q8 = (lane >> 4) * 8;
    int split = blockIdx.x;
    int b0 = blockIdx.y * 32;
    int k0 = split * 512;
    f32x4 a00 = {}, a01 = {}, a10 = {}, a11 = {};
    const unsigned short* x0 = xb + (size_t)(b0 + l15) * 8192 + k0 + q8;
    const unsigned short* x1 = x0 + (size_t)16 * 8192;
    const unsigned short* w0 = Abf + (size_t)(w * 32 + l15) * 8192 + k0 + q8;
    const unsigned short* w1 = w0 + (size_t)16 * 8192;
#pragma unroll 4
    for (int ks = 0; ks < 16; ++ks) {
        int kk = ks * 32;
        bf16x8 af0 = *(const bf16x8*)(x0 + kk);
        bf16x8 af1 = *(const bf16x8*)(x1 + kk);
        bf16x8 bf0 = *(const bf16x8*)(w0 + kk);
        bf16x8 bf1 = *(const bf16x8*)(w1 + kk);
        a00 = __builtin_amdgcn_mfma_f32_16x16x32_bf16(af0, bf0, a00, 0, 0, 0);
        a01 = __builtin_amdgcn_mfma_f32_16x16x32_bf16(af0, bf1, a01, 0, 0, 0);
        a10 = __builtin_amdgcn_mfma_f32_16x16x32_bf16(af1, bf0, a10, 0, 0, 0);
        a11 = __builtin_amdgcn_mfma_f32_16x16x32_bf16(af1, bf1, a11, 0, 0, 0);
    }
    int row = (lane >> 4) * 4;
    size_t base = (size_t)split * (B_ * 128);
    float* g00 = Axpart + base + (size_t)(b0 + row) * 128 + w * 32 + l15;
    float* g10 = Axpart + base + (size_t)(b0 + 16 + row) * 128 + w * 32 + l15;
#pragma unroll
    for (int r = 0; r < 4; ++r) {
        g00[(size_t)r * 128] = a00[r];
        g00[(size_t)r * 128 + 16] = a01[r];
        g10[(size_t)r * 128] = a10[r];
        g10[(size_t)r * 128 + 16] = a11[r];
    }
}

// ---------------------------------------------------------------------------
// per-step epilogue
__global__ __launch_bounds__(128) void k_small3(const float* Axpart, const float* uin,
                                                const float* y, const float* le,
                                                float* z, float* u, float* uout, int last) {
    __shared__ float red[2];
    int b = blockIdx.x, t = threadIdx.x;
    size_t idx = (size_t)b * 128 + t;
    float ax = 0.f;
#pragma unroll
    for (int s = 0; s < NS3; ++s) ax += Axpart[(size_t)s * 131072 + idx];
    float uo = uin[idx], yv = y[idx];
    float v = ax + uo - yv;
    float sq = v * v;
    for (int off = 32; off > 0; off >>= 1) sq += __shfl_down(sq, off, 64);
    if ((t & 63) == 0) red[t >> 6] = sq;
    __syncthreads();
    float tot = red[0] + red[1];
    float eps = expf(le[0]);
    float scale = fminf(1.f, eps / (sqrtf(tot) + 1e-12f));
    float zv = yv + v * scale;
    float un = uo + ax - zv;
    z[idx] = zv;
    u[idx] = un;
    if (last) uout[idx] = un;
}

// ---------------------------------------------------------------------------
extern "C" void kernel_launch(void* const* d_in, const int* in_sizes, int n_in,
                              void* d_out, int out_size, void* d_ws, size_t ws_size,
                              hipStream_t stream) {
    const float* rn  = (const float*)d_in[0];   // (B,2,N)
    const float* y   = (const float*)d_in[1];   // (B,2,M)
    const float* uin = (const float*)d_in[2];   // (B,2,M)
    const float* A   = (const float*)d_in[3];   // (2,M,N)
    const float* lr  = (const float*)d_in[4];   // log_rho
    const float* le  = (const float*)d_in[5];   // log_epsilon

    float* out = (float*)d_out;
    float* ws  = (float*)d_ws;

    float* Gpart  = ws;                          // NSG*B*128      = 4,194,304 f
    float* Axpart = Gpart + (size_t)NSG * 131072;      // NS3*B*128 = 2,097,152 f
    float* S      = Axpart + (size_t)NS3 * 131072;     // 8192
    float* AAHT   = S + 8192;                    // 8192
    float* Wt     = AAHT + 8192;                 // 8192
    float* z      = Wt + 8192;                   // 131072
    float* u      = z + 131072;                  // 131072
    unsigned short* qb  = (unsigned short*)(u + 131072);   // 131072 us
    unsigned short* xb  = qb + 131072;           // B*N          = 8,388,608 us
    unsigned short* WgT = xb + (size_t)B_ * N_;  // 128*16384    = 2,097,152 us
    unsigned short* Abf = WgT + 2097152;         // 2*64*8192    = 1,048,576 us
    unsigned short* ATb = Abf + 1048576;         // 8192*128     = 1,048,576 us
    float* uout = out + (size_t)B_ * 2 * N_;

    k_zero_imag<<<dim3(8, B_), 256, 0, stream>>>(out);
    k_cvtA<<<512, 256, 0, stream>>>(A, Abf);
    k_prep_wg<<<dim3(128, 8), 256, 0, stream>>>(A, WgT);
    k_transpA<<<128, 256, 0, stream>>>(A, ATb);
    k_Sbuild<<<2080, 256, 0, stream>>>(A, lr, S, AAHT);
    k_invert<<<1, 1024, 0, stream>>>(S, Wt);
    k_G<<<dim3(NSG, 32), 256, 0, stream>>>(rn, WgT, Gpart);

    for (int step = 0; step < 3; ++step) {
        const float* zp = (step == 0) ? y   : z;
        const float* up = (step == 0) ? uin : u;
        k_small12<<<256, 256, 0, stream>>>(Gpart, AAHT, Wt, zp, up, lr, qb);
        k_H2<<<dim3(8, 64), 256, 0, stream>>>(qb, ATb, rn, out, xb);
        k_H3<<<dim3(NS3, 32), 256, 0, stream>>>(xb, Abf, Axpart);
        k_small3<<<B_, 128, 0, stream>>>(Axpart, up, y, le, z, u, uout, step == 2 ? 1 : 0);
    }
}